// Round 13
// baseline (174.160 us; speedup 1.0000x reference)
//
#include <hip/hip_runtime.h>
#include <hip/hip_bf16.h>

#define Bc 32
#define Nc 1024
#define Fc 32
#define Dc 64
#define Hc 64

typedef __bf16 bf16;
typedef __bf16 bf16x4 __attribute__((ext_vector_type(4)));
typedef __bf16 bf16x8 __attribute__((ext_vector_type(8)));
typedef float  f32x4  __attribute__((ext_vector_type(4)));

#define MS 72                 // bf16 LDS row stride (144B, 16B-aligned)
#define LDS_RND_NONF 18432    // muS[64][72] + W2s[64][72]
#define LDS_RND_FIN  37376    // muHi,muLo,WHi,WLo [64][72] + rpart[2][64]f

// Fragment-major layouts (16B per lane, coalesced wave loads):
//   Afrag[g][k0][lane][8] : g=n>>4, k0=k>>5, lane=(n&15)+16*((k>>3)&3), j=k&7
//   Xfrag[b][g][k0][lane][8]: g=d>>4, k0=n>>5, lane=(d&15)+16*((n>>3)&3), j=n&7

// ---------------------------------------------------------------------------
// k_init: blocks 0..1023 (n=id): Afrag row n (binarized) + C3[n][:]
//         block 1024: W2bf, musum zero, c2base
//         blocks 1025..1536: mu1-part: mu_1 = relu(xv@mu1); Xfrag0 = mu_1@W2^T
// ---------------------------------------------------------------------------
__global__ void k_init(const float* __restrict__ adj, const float* __restrict__ W4,
                       const float* __restrict__ b4, const float* __restrict__ W3,
                       const float* __restrict__ b3, const float* __restrict__ b2,
                       const float* __restrict__ W2, const float* __restrict__ option,
                       const float* __restrict__ Wq2, const float* __restrict__ bq2,
                       const float* __restrict__ Wreg, const float* __restrict__ breg,
                       const float* __restrict__ xv, const float* __restrict__ mu1w,
                       bf16* __restrict__ Afrag, float* __restrict__ C3,
                       bf16* __restrict__ W2bf, float* __restrict__ c2base,
                       float* __restrict__ musum,
                       float* __restrict__ mu_1, bf16* __restrict__ Xfrag0) {
    const int id = blockIdx.x, t = threadIdx.x;
    __shared__ char smem[39424];
    if (id < 1024) {
        const int n = id;
        float* red   = (float*)smem;
        float* mu4_s = red + 256;
        const float* arow = adj + (size_t)n * Nc;
        {   // binarize row n into Afrag
            const int m0 = t * 4;
            const float4 a = *(const float4*)&arow[m0];
            bf16x4 o;
            o[0] = (bf16)((a.x > 0.f) ? 1.f : 0.f);
            o[1] = (bf16)((a.y > 0.f) ? 1.f : 0.f);
            o[2] = (bf16)((a.z > 0.f) ? 1.f : 0.f);
            o[3] = (bf16)((a.w > 0.f) ? 1.f : 0.f);
            const int g = n >> 4, lm = n & 15;
            const int k0 = m0 >> 5, q = (m0 & 31) >> 3, j = m0 & 7;
            *(bf16x4*)&Afrag[(size_t)((g * 32 + k0) * 64 + lm + 16 * q) * 8 + j] = o;
        }
        const int e = t & 63, g = t >> 6;
        const float w4e = W4[e], b4e = b4[e];
        float acc = 0.f;
        const float4* arow4 = (const float4*)(arow + g * 256);
#pragma unroll 8
        for (int j = 0; j < 64; ++j) {
            const float4 av = arow4[j];
            acc += fmaxf(fmaf(av.x, w4e, b4e), 0.f);
            acc += fmaxf(fmaf(av.y, w4e, b4e), 0.f);
            acc += fmaxf(fmaf(av.z, w4e, b4e), 0.f);
            acc += fmaxf(fmaf(av.w, w4e, b4e), 0.f);
        }
        red[t] = acc;
        __syncthreads();
        if (g == 0) mu4_s[e] = red[e] + red[64 + e] + red[128 + e] + red[192 + e];
        __syncthreads();
        if (t < 64) {
            const int d = t;
            float a = b3[d] + b2[d];
#pragma unroll
            for (int ee = 0; ee < 64; ++ee) a = fmaf(mu4_s[ee], W3[d * 64 + ee], a);
            C3[n * 64 + d] = a;
        }
    } else if (id == 1024) {
        for (int j = t * 16; j < t * 16 + 16; ++j) W2bf[j] = (bf16)W2[j];
        for (int i = t; i < 2048; i += 256) musum[i] = 0.f;
        for (int i = t; i < 2048; i += 256) {
            const int b = i >> 6, h = i & 63;
            const float opt = option[b];
            float a = breg[h];
#pragma unroll
            for (int j = 0; j < 64; ++j)
                a = fmaf(fmaf(opt, Wq2[j], bq2[j]), Wreg[h * 128 + 64 + j], a);
            c2base[i] = a;
        }
    } else {
        // ---- mu1-part: 64-row tile ----
        const int idx = id - 1025, nb = idx & 15, b = idx >> 4;
        const int n0 = nb * 64;
        const int l = t & 63, wv = t >> 6, lm = l & 15, q = l >> 4;
        bf16* W2s = (bf16*)smem;              // [64][72]
        bf16* xhi = (bf16*)(smem + 9216);
        bf16* xlo = (bf16*)(smem + 14336);
        bf16* whi = (bf16*)(smem + 19456);
        bf16* wlo = (bf16*)(smem + 24576);
        bf16* muS = (bf16*)(smem + 29696);    // [64][72]
        {
            const int row = t >> 2, f0 = (t & 3) * 8;
            const float* src = &xv[((size_t)b * Nc + n0 + row) * Fc + f0];
            const float4 v0 = *(const float4*)src;
            const float4 v1 = *(const float4*)(src + 4);
            bf16x8 hi, lo;
            float vv[8] = {v0.x, v0.y, v0.z, v0.w, v1.x, v1.y, v1.z, v1.w};
#pragma unroll
            for (int j = 0; j < 8; ++j) { hi[j] = (bf16)vv[j]; lo[j] = (bf16)(vv[j] - (float)hi[j]); }
            *(bf16x8*)&xhi[row * 40 + f0] = hi;
            *(bf16x8*)&xlo[row * 40 + f0] = lo;
        }
        {
            const int d = t >> 2, f0 = (t & 3) * 8;
#pragma unroll
            for (int j = 0; j < 8; ++j) {
                const float v = mu1w[(f0 + j) * Dc + d];
                const bf16 hi = (bf16)v;
                whi[d * 40 + f0 + j] = hi;
                wlo[d * 40 + f0 + j] = (bf16)(v - (float)hi);
            }
        }
        {   // W2s[d][e] from fp32 W2
            const int row = t >> 2, c0 = (t & 3) * 16;
            const float4 v0 = *(const float4*)&W2[row * 64 + c0];
            const float4 v1 = *(const float4*)&W2[row * 64 + c0 + 4];
            const float4 v2 = *(const float4*)&W2[row * 64 + c0 + 8];
            const float4 v3 = *(const float4*)&W2[row * 64 + c0 + 12];
            bf16x8 p0, p1;
            p0[0]=(bf16)v0.x; p0[1]=(bf16)v0.y; p0[2]=(bf16)v0.z; p0[3]=(bf16)v0.w;
            p0[4]=(bf16)v1.x; p0[5]=(bf16)v1.y; p0[6]=(bf16)v1.z; p0[7]=(bf16)v1.w;
            p1[0]=(bf16)v2.x; p1[1]=(bf16)v2.y; p1[2]=(bf16)v2.z; p1[3]=(bf16)v2.w;
            p1[4]=(bf16)v3.x; p1[5]=(bf16)v3.y; p1[6]=(bf16)v3.z; p1[7]=(bf16)v3.w;
            *(bf16x8*)&W2s[row * MS + c0] = p0;
            *(bf16x8*)&W2s[row * MS + c0 + 8] = p1;
        }
        __syncthreads();
        f32x4 acc[4];
#pragma unroll
        for (int ct = 0; ct < 4; ++ct)
#pragma unroll
            for (int r = 0; r < 4; ++r) acc[ct][r] = 0.f;
        {
            const bf16x8 aHi = *(const bf16x8*)&xhi[(wv * 16 + lm) * 40 + q * 8];
            const bf16x8 aLo = *(const bf16x8*)&xlo[(wv * 16 + lm) * 40 + q * 8];
#pragma unroll
            for (int ct = 0; ct < 4; ++ct) {
                const bf16x8 bHi = *(const bf16x8*)&whi[(ct * 16 + lm) * 40 + q * 8];
                const bf16x8 bLo = *(const bf16x8*)&wlo[(ct * 16 + lm) * 40 + q * 8];
                acc[ct] = __builtin_amdgcn_mfma_f32_16x16x32_bf16(aHi, bHi, acc[ct], 0, 0, 0);
                acc[ct] = __builtin_amdgcn_mfma_f32_16x16x32_bf16(aLo, bHi, acc[ct], 0, 0, 0);
                acc[ct] = __builtin_amdgcn_mfma_f32_16x16x32_bf16(aHi, bLo, acc[ct], 0, 0, 0);
            }
        }
#pragma unroll
        for (int ct = 0; ct < 4; ++ct) {
            const int col = ct * 16 + lm;
#pragma unroll
            for (int r = 0; r < 4; ++r) {
                const int row = wv * 16 + q * 4 + r;
                const float v = fmaxf(acc[ct][r], 0.f);
                mu_1[((size_t)b * Nc + n0 + row) * Dc + col] = v;
                muS[row * MS + col] = (bf16)v;
            }
        }
        __syncthreads();
        f32x4 xacc[4];
#pragma unroll
        for (int ct = 0; ct < 4; ++ct)
#pragma unroll
            for (int r = 0; r < 4; ++r) xacc[ct][r] = 0.f;
#pragma unroll
        for (int s = 0; s < 2; ++s) {
            bf16x8 a = *(const bf16x8*)&muS[(wv * 16 + lm) * MS + s * 32 + q * 8];
#pragma unroll
            for (int ct = 0; ct < 4; ++ct) {
                bf16x8 bv = *(const bf16x8*)&W2s[(ct * 16 + lm) * MS + s * 32 + q * 8];
                xacc[ct] = __builtin_amdgcn_mfma_f32_16x16x32_bf16(a, bv, xacc[ct], 0, 0, 0);
            }
        }
        const int k0 = nb * 2 + (wv >> 1);
        const int q_c = (wv & 1) * 2 + (q >> 1);
        const int j0 = (q & 1) * 4;
#pragma unroll
        for (int ct = 0; ct < 4; ++ct) {
            bf16x4 p;
#pragma unroll
            for (int r = 0; r < 4; ++r) p[r] = (bf16)xacc[ct][r];
            *(bf16x4*)&Xfrag0[(size_t)b * 65536
                              + (size_t)((ct * 32 + k0) * 64 + lm + 16 * q_c) * 8 + j0] = p;
        }
    }
}

// ---------------------------------------------------------------------------
// k_round: barrier-free coalesced K-loop on fragment-major A/X (R10 config:
// 64-row tiles, grid (Bc,16) = 512 blocks, 2 blocks/CU). 256 thr = 4 waves
// (rh = n-half, ch = d-half). Epilogue operands preloaded before the K-loop.
// Epilogue: mu = relu(mu_1+P+C3); non-final: Xfrag_out = mu@W2^T; final: head.
// ---------------------------------------------------------------------------
template <bool FINAL>
__global__ __launch_bounds__(256, 2)
void k_round(const bf16* __restrict__ Afrag, const bf16* __restrict__ Xfr_in,
             const float* __restrict__ mu_1, const float* __restrict__ C3,
             const bf16* __restrict__ W2bf, bf16* __restrict__ Xfr_out,
             const float* __restrict__ Wreg, const float* __restrict__ c2base,
             const float* __restrict__ Wq, const float* __restrict__ bq,
             float* __restrict__ musum, float* __restrict__ out) {
    const int b = blockIdx.x, nb = blockIdx.y, t = threadIdx.x;
    const int n0 = nb * 64;
    const int l = t & 63, wv = t >> 6, lm = l & 15, q = l >> 4;
    const int rh = wv & 1, ch = wv >> 1;
    extern __shared__ char smem[];
    bf16* muHi = (bf16*)smem;                     // [64][72]
    bf16* muLo = (bf16*)(smem + 9216);            // FINAL only
    bf16* WHi  = (bf16*)(smem + (FINAL ? 18432 : 9216));
    bf16* WLo  = (bf16*)(smem + 27648);           // FINAL only
    float* rpart = (float*)(smem + 36864);        // FINAL [2][64]

    if (!FINAL) {
#pragma unroll
        for (int i = 0; i < 2; ++i) {
            int g = i * 256 + t, row = g >> 3, c = g & 7;
            *(bf16x8*)&WHi[row * MS + c * 8] = *(const bf16x8*)&W2bf[row * 64 + c * 8];
        }
    } else {
#pragma unroll
        for (int i = 0; i < 4; ++i) {
            int g = i * 1024 + t * 4, h = g >> 6, d = g & 63;
            const float4 w4 = *(const float4*)&Wreg[h * 128 + d];
            bf16x4 ohi, olo;
            ohi[0] = (bf16)w4.x; olo[0] = (bf16)(w4.x - (float)ohi[0]);
            ohi[1] = (bf16)w4.y; olo[1] = (bf16)(w4.y - (float)ohi[1]);
            ohi[2] = (bf16)w4.z; olo[2] = (bf16)(w4.z - (float)ohi[2]);
            ohi[3] = (bf16)w4.w; olo[3] = (bf16)(w4.w - (float)ohi[3]);
            *(bf16x4*)&WHi[h * MS + d] = ohi;
            *(bf16x4*)&WLo[h * MS + d] = olo;
        }
    }

    // ---- K-loop: coalesced fragment streaming, no barriers ----
    f32x4 acc[2][2];
#pragma unroll
    for (int rt = 0; rt < 2; ++rt)
#pragma unroll
        for (int ct = 0; ct < 2; ++ct)
#pragma unroll
            for (int r = 0; r < 4; ++r) acc[rt][ct][r] = 0.f;

    const int gA = nb * 4 + rh * 2;
    const bf16* pa0 = Afrag + (size_t)(gA + 0) * 32 * 512 + l * 8;
    const bf16* pa1 = Afrag + (size_t)(gA + 1) * 32 * 512 + l * 8;
    const bf16* px0 = Xfr_in + (size_t)b * 65536 + (size_t)(ch * 2 + 0) * 32 * 512 + l * 8;
    const bf16* px1 = Xfr_in + (size_t)b * 65536 + (size_t)(ch * 2 + 1) * 32 * 512 + l * 8;

    // preload epilogue operands (independent of the K-loop; hides epilogue latency)
    float pmu[2][2][4], pc3[2][2][4];
#pragma unroll
    for (int rt = 0; rt < 2; ++rt)
#pragma unroll
        for (int ct = 0; ct < 2; ++ct) {
            const int col = ch * 32 + ct * 16 + lm;
#pragma unroll
            for (int r = 0; r < 4; ++r) {
                const int n = n0 + rh * 32 + rt * 16 + q * 4 + r;
                pmu[rt][ct][r] = mu_1[((size_t)b * Nc + n) * Dc + col];
                pc3[rt][ct][r] = C3[n * 64 + col];
            }
        }

#pragma unroll 4
    for (int k0 = 0; k0 < 32; ++k0) {
        const int o = k0 * 512;
        bf16x8 a0 = *(const bf16x8*)&pa0[o];
        bf16x8 a1 = *(const bf16x8*)&pa1[o];
        bf16x8 x0 = *(const bf16x8*)&px0[o];
        bf16x8 x1 = *(const bf16x8*)&px1[o];
        acc[0][0] = __builtin_amdgcn_mfma_f32_16x16x32_bf16(a0, x0, acc[0][0], 0, 0, 0);
        acc[0][1] = __builtin_amdgcn_mfma_f32_16x16x32_bf16(a0, x1, acc[0][1], 0, 0, 0);
        acc[1][0] = __builtin_amdgcn_mfma_f32_16x16x32_bf16(a1, x0, acc[1][0], 0, 0, 0);
        acc[1][1] = __builtin_amdgcn_mfma_f32_16x16x32_bf16(a1, x1, acc[1][1], 0, 0, 0);
    }

    // ---- epilogue: mu = relu(mu_1 + P + C3) ----
    float vals[2][2][4];
#pragma unroll
    for (int rt = 0; rt < 2; ++rt)
#pragma unroll
        for (int ct = 0; ct < 2; ++ct)
#pragma unroll
            for (int r = 0; r < 4; ++r)
                vals[rt][ct][r] = fmaxf(pmu[rt][ct][r] + acc[rt][ct][r] + pc3[rt][ct][r], 0.f);

#pragma unroll
    for (int rt = 0; rt < 2; ++rt)
#pragma unroll
        for (int ct = 0; ct < 2; ++ct) {
            const int col = ch * 32 + ct * 16 + lm;
#pragma unroll
            for (int r = 0; r < 4; ++r) {
                const int row = rh * 32 + rt * 16 + q * 4 + r;
                const float v = vals[rt][ct][r];
                const bf16 hi = (bf16)v;
                muHi[row * MS + col] = hi;
                if (FINAL) muLo[row * MS + col] = (bf16)(v - (float)hi);
            }
        }
    if (FINAL) {
#pragma unroll
        for (int ct = 0; ct < 2; ++ct) {
            float s = 0.f;
#pragma unroll
            for (int rt = 0; rt < 2; ++rt)
#pragma unroll
                for (int r = 0; r < 4; ++r) s += vals[rt][ct][r];
            s += __shfl_xor(s, 16);
            s += __shfl_xor(s, 32);
            if (q == 0) atomicAdd(&musum[b * 64 + ch * 32 + ct * 16 + lm], s);
        }
    }
    __syncthreads();

    f32x4 xacc[2][2];
#pragma unroll
    for (int rt = 0; rt < 2; ++rt)
#pragma unroll
        for (int ct = 0; ct < 2; ++ct)
#pragma unroll
            for (int r = 0; r < 4; ++r) xacc[rt][ct][r] = 0.f;

    if (!FINAL) {
#pragma unroll
        for (int s = 0; s < 2; ++s) {
            bf16x8 aM[2], bW[2];
#pragma unroll
            for (int rt = 0; rt < 2; ++rt)
                aM[rt] = *(const bf16x8*)&muHi[(rh * 32 + rt * 16 + lm) * MS + s * 32 + q * 8];
#pragma unroll
            for (int ct = 0; ct < 2; ++ct)
                bW[ct] = *(const bf16x8*)&WHi[(ch * 32 + ct * 16 + lm) * MS + s * 32 + q * 8];
#pragma unroll
            for (int rt = 0; rt < 2; ++rt)
#pragma unroll
                for (int ct = 0; ct < 2; ++ct)
                    xacc[rt][ct] = __builtin_amdgcn_mfma_f32_16x16x32_bf16(aM[rt], bW[ct],
                                                                           xacc[rt][ct], 0, 0, 0);
        }
        const int k0 = nb * 2 + rh;
        const int q_c0 = (q >> 1), j0 = (q & 1) * 4;
#pragma unroll
        for (int rt = 0; rt < 2; ++rt)
#pragma unroll
            for (int ct = 0; ct < 2; ++ct) {
                bf16x4 p;
#pragma unroll
                for (int r = 0; r < 4; ++r) p[r] = (bf16)xacc[rt][ct][r];
                *(bf16x4*)&Xfr_out[(size_t)b * 65536
                    + (size_t)(((ch * 2 + ct) * 32 + k0) * 64 + lm + 16 * (rt * 2 + q_c0)) * 8
                    + j0] = p;
            }
    } else {
        // head: P2 = muHi@WHi + muLo@WHi + muHi@WLo (split precision)
#pragma unroll
        for (int s = 0; s < 2; ++s) {
            bf16x8 aH[2], aL[2], bH[2], bL[2];
#pragma unroll
            for (int rt = 0; rt < 2; ++rt) {
                const int ao = (rh * 32 + rt * 16 + lm) * MS + s * 32 + q * 8;
                aH[rt] = *(const bf16x8*)&muHi[ao];
                aL[rt] = *(const bf16x8*)&muLo[ao];
            }
#pragma unroll
            for (int ct = 0; ct < 2; ++ct) {
                const int bo = (ch * 32 + ct * 16 + lm) * MS + s * 32 + q * 8;
                bH[ct] = *(const bf16x8*)&WHi[bo];
                bL[ct] = *(const bf16x8*)&WLo[bo];
            }
#pragma unroll
            for (int rt = 0; rt < 2; ++rt)
#pragma unroll
                for (int ct = 0; ct < 2; ++ct) {
                    xacc[rt][ct] = __builtin_amdgcn_mfma_f32_16x16x32_bf16(aH[rt], bH[ct],
                                                                           xacc[rt][ct], 0, 0, 0);
                    xacc[rt][ct] = __builtin_amdgcn_mfma_f32_16x16x32_bf16(aL[rt], bH[ct],
                                                                           xacc[rt][ct], 0, 0, 0);
                    xacc[rt][ct] = __builtin_amdgcn_mfma_f32_16x16x32_bf16(aH[rt], bL[ct],
                                                                           xacc[rt][ct], 0, 0, 0);
                }
        }
        const float bq0 = bq[0];
        float rowsum[2][4] = {{0.f, 0.f, 0.f, 0.f}, {0.f, 0.f, 0.f, 0.f}};
#pragma unroll
        for (int ct = 0; ct < 2; ++ct) {
            const int h = ch * 32 + ct * 16 + lm;
            const float c2 = c2base[b * 64 + h];
            const float wqh = Wq[h];
#pragma unroll
            for (int rt = 0; rt < 2; ++rt)
#pragma unroll
                for (int r = 0; r < 4; ++r)
                    rowsum[rt][r] += fmaxf(xacc[rt][ct][r] + c2, 0.f) * wqh;
        }
#pragma unroll
        for (int rt = 0; rt < 2; ++rt)
#pragma unroll
            for (int r = 0; r < 4; ++r) {
                float v = rowsum[rt][r];
                v += __shfl_xor(v, 1);
                v += __shfl_xor(v, 2);
                v += __shfl_xor(v, 4);
                v += __shfl_xor(v, 8);
                if (lm == 0) rpart[ch * 64 + rh * 32 + rt * 16 + q * 4 + r] = v;
            }
        __syncthreads();
        if (t < 64)
            out[(size_t)b * (Nc + 1) + n0 + t] = rpart[t] + rpart[64 + t] + bq0;
    }
}

// ---------------------------------------------------------------------------
// k_tail: mean row. grid B, block 64 (fp32)
// ---------------------------------------------------------------------------
__global__ void k_tail(const float* __restrict__ musum, const float* __restrict__ Wq1,
                       const float* __restrict__ bq1, const float* __restrict__ Wreg,
                       const float* __restrict__ c2base, const float* __restrict__ Wq,
                       const float* __restrict__ bq, float* __restrict__ out) {
    const int b = blockIdx.x, l = threadIdx.x;
    __shared__ float mean_s[64];
    __shared__ float mp[64];
    mean_s[l] = musum[b * 64 + l] * (1.f / Nc);
    __syncthreads();
    float a = bq1[l];
#pragma unroll
    for (int e = 0; e < 64; ++e) a = fmaf(mean_s[e], Wq1[l * 64 + e], a);
    mp[l] = fmaxf(a, 0.f);
    __syncthreads();
    float h = c2base[b * 64 + l];
#pragma unroll
    for (int d = 0; d < 64; ++d) h = fmaf(mp[d], Wreg[l * 128 + d], h);
    float v = fmaxf(h, 0.f) * Wq[l];
#pragma unroll
    for (int off = 32; off; off >>= 1) v += __shfl_down(v, off);
    if (l == 0) out[(size_t)b * (Nc + 1) + Nc] = v + bq[0];
}

// ---------------------------------------------------------------------------
extern "C" void kernel_launch(void* const* d_in, const int* in_sizes, int n_in,
                              void* d_out, int out_size, void* d_ws, size_t ws_size,
                              hipStream_t stream) {
    const float* xv     = (const float*)d_in[0];
    const float* option = (const float*)d_in[1];
    const float* adj    = (const float*)d_in[2];
    const float* mu1w   = (const float*)d_in[3];
    const float* W2     = (const float*)d_in[4];
    const float* b2     = (const float*)d_in[5];
    const float* W3     = (const float*)d_in[6];
    const float* b3     = (const float*)d_in[7];
    const float* W4     = (const float*)d_in[8];
    const float* b4     = (const float*)d_in[9];
    const float* Wq1    = (const float*)d_in[10];
    const float* bq1    = (const float*)d_in[11];
    const float* Wq2    = (const float*)d_in[12];
    const float* bq2    = (const float*)d_in[13];
    const float* Wreg   = (const float*)d_in[14];
    const float* breg   = (const float*)d_in[15];
    const float* Wq     = (const float*)d_in[16];
    const float* bq     = (const float*)d_in[17];
    float* out = (float*)d_out;

    float* ws = (float*)d_ws;
    const size_t MU = (size_t)Bc * Nc * Dc;          // 2,097,152
    float* mu_1     = ws;
    float* C3       = ws + MU;                       // 65536
    float* c2base   = C3 + 65536;                    // 2048
    float* musum    = c2base + 2048;                 // 2048
    bf16*  Afrag    = (bf16*)(musum + 2048);         // 1M bf16
    bf16*  W2bf     = Afrag + (size_t)Nc * Nc;       // 4096 bf16
    bf16*  Xf0      = W2bf + 4096;                   // B*64K bf16
    bf16*  Xf1      = Xf0 + MU;

    k_init<<<1537, 256, 0, stream>>>(adj, W4, b4, W3, b3, b2, W2, option, Wq2, bq2,
                                     Wreg, breg, xv, mu1w,
                                     Afrag, C3, W2bf, c2base, musum, mu_1, Xf0);
    k_round<false><<<dim3(Bc, 16), 256, LDS_RND_NONF, stream>>>(
        Afrag, Xf0, mu_1, C3, W2bf, Xf1,
        nullptr, nullptr, nullptr, nullptr, nullptr, nullptr);
    k_round<false><<<dim3(Bc, 16), 256, LDS_RND_NONF, stream>>>(
        Afrag, Xf1, mu_1, C3, W2bf, Xf0,
        nullptr, nullptr, nullptr, nullptr, nullptr, nullptr);
    k_round<true><<<dim3(Bc, 16), 256, LDS_RND_FIN, stream>>>(
        Afrag, Xf0, mu_1, C3, nullptr, nullptr,
        Wreg, c2base, Wq, bq, musum, out);
    k_tail<<<Bc, 64, 0, stream>>>(musum, Wq1, bq1, Wreg, c2base, Wq, bq, out);
}

// Round 14
// 152.045 us; speedup vs baseline: 1.1455x; 1.1455x over previous
//
#include <hip/hip_runtime.h>
#include <hip/hip_bf16.h>

#define Bc 32
#define Nc 1024
#define Fc 32
#define Dc 64
#define Hc 64

typedef __bf16 bf16;
typedef __bf16 bf16x4 __attribute__((ext_vector_type(4)));
typedef __bf16 bf16x8 __attribute__((ext_vector_type(8)));
typedef float  f32x4  __attribute__((ext_vector_type(4)));

#define MS 72                 // bf16 LDS row stride (144B, 16B-aligned)
#define LDS_RND_NONF 18432    // muS[64][72] + W2s[64][72]
#define LDS_RND_FIN  37376    // muHi,muLo,WHi,WLo [64][72] + rpart[2][64]f

// Fragment-major layouts (16B per lane, coalesced wave loads):
//   Afrag[g][k0][lane][8] : g=n>>4, k0=k>>5, lane=(n&15)+16*((k>>3)&3), j=k&7
//   Xfrag[b][g][k0][lane][8]: g=d>>4, k0=n>>5, lane=(d&15)+16*((n>>3)&3), j=n&7
// Afrag total = 64*32*512 = 1M bf16; Xfrag per b = 4*32*512 = 64K bf16.

// ---------------------------------------------------------------------------
// k_init: blocks 0..1023 (n=id): Afrag row n (binarized) + C3[n][:]
//         block 1024: W2bf, musum zero, c2base
//         blocks 1025..1536: mu1-part (idx=id-1025: nb=idx&15, b=idx>>4):
//             mu_1 = relu(xv@mu1) split-precision MFMA; Xfrag0 = mu_1@W2^T
// ---------------------------------------------------------------------------
__global__ void k_init(const float* __restrict__ adj, const float* __restrict__ W4,
                       const float* __restrict__ b4, const float* __restrict__ W3,
                       const float* __restrict__ b3, const float* __restrict__ b2,
                       const float* __restrict__ W2, const float* __restrict__ option,
                       const float* __restrict__ Wq2, const float* __restrict__ bq2,
                       const float* __restrict__ Wreg, const float* __restrict__ breg,
                       const float* __restrict__ xv, const float* __restrict__ mu1w,
                       bf16* __restrict__ Afrag, float* __restrict__ C3,
                       bf16* __restrict__ W2bf, float* __restrict__ c2base,
                       float* __restrict__ musum,
                       float* __restrict__ mu_1, bf16* __restrict__ Xfrag0) {
    const int id = blockIdx.x, t = threadIdx.x;
    __shared__ char smem[39424];
    if (id < 1024) {
        const int n = id;
        float* red   = (float*)smem;
        float* mu4_s = red + 256;
        const float* arow = adj + (size_t)n * Nc;
        {   // binarize row n into Afrag
            const int m0 = t * 4;
            const float4 a = *(const float4*)&arow[m0];
            bf16x4 o;
            o[0] = (bf16)((a.x > 0.f) ? 1.f : 0.f);
            o[1] = (bf16)((a.y > 0.f) ? 1.f : 0.f);
            o[2] = (bf16)((a.z > 0.f) ? 1.f : 0.f);
            o[3] = (bf16)((a.w > 0.f) ? 1.f : 0.f);
            const int g = n >> 4, lm = n & 15;
            const int k0 = m0 >> 5, q = (m0 & 31) >> 3, j = m0 & 7;
            *(bf16x4*)&Afrag[(size_t)((g * 32 + k0) * 64 + lm + 16 * q) * 8 + j] = o;
        }
        const int e = t & 63, g = t >> 6;
        const float w4e = W4[e], b4e = b4[e];
        float acc = 0.f;
        const float4* arow4 = (const float4*)(arow + g * 256);
#pragma unroll 8
        for (int j = 0; j < 64; ++j) {
            const float4 av = arow4[j];
            acc += fmaxf(fmaf(av.x, w4e, b4e), 0.f);
            acc += fmaxf(fmaf(av.y, w4e, b4e), 0.f);
            acc += fmaxf(fmaf(av.z, w4e, b4e), 0.f);
            acc += fmaxf(fmaf(av.w, w4e, b4e), 0.f);
        }
        red[t] = acc;
        __syncthreads();
        if (g == 0) mu4_s[e] = red[e] + red[64 + e] + red[128 + e] + red[192 + e];
        __syncthreads();
        if (t < 64) {
            const int d = t;
            float a = b3[d] + b2[d];
#pragma unroll
            for (int ee = 0; ee < 64; ++ee) a = fmaf(mu4_s[ee], W3[d * 64 + ee], a);
            C3[n * 64 + d] = a;
        }
    } else if (id == 1024) {
        for (int j = t * 16; j < t * 16 + 16; ++j) W2bf[j] = (bf16)W2[j];
        for (int i = t; i < 2048; i += 256) musum[i] = 0.f;
        for (int i = t; i < 2048; i += 256) {
            const int b = i >> 6, h = i & 63;
            const float opt = option[b];
            float a = breg[h];
#pragma unroll
            for (int j = 0; j < 64; ++j)
                a = fmaf(fmaf(opt, Wq2[j], bq2[j]), Wreg[h * 128 + 64 + j], a);
            c2base[i] = a;
        }
    } else {
        // ---- mu1-part: 64-row tile ----
        const int idx = id - 1025, nb = idx & 15, b = idx >> 4;
        const int n0 = nb * 64;
        const int l = t & 63, wv = t >> 6, lm = l & 15, q = l >> 4;
        bf16* W2s = (bf16*)smem;              // [64][72] = 9216
        bf16* xhi = (bf16*)(smem + 9216);     // [64][40] = 5120
        bf16* xlo = (bf16*)(smem + 14336);
        bf16* whi = (bf16*)(smem + 19456);
        bf16* wlo = (bf16*)(smem + 24576);    // end 29696
        bf16* muS = (bf16*)(smem + 29696);    // [64][72] = 9216, end 38912
        {
            const int row = t >> 2, f0 = (t & 3) * 8;
            const float* src = &xv[((size_t)b * Nc + n0 + row) * Fc + f0];
            const float4 v0 = *(const float4*)src;
            const float4 v1 = *(const float4*)(src + 4);
            bf16x8 hi, lo;
            float vv[8] = {v0.x, v0.y, v0.z, v0.w, v1.x, v1.y, v1.z, v1.w};
#pragma unroll
            for (int j = 0; j < 8; ++j) { hi[j] = (bf16)vv[j]; lo[j] = (bf16)(vv[j] - (float)hi[j]); }
            *(bf16x8*)&xhi[row * 40 + f0] = hi;
            *(bf16x8*)&xlo[row * 40 + f0] = lo;
        }
        {
            const int d = t >> 2, f0 = (t & 3) * 8;
#pragma unroll
            for (int j = 0; j < 8; ++j) {
                const float v = mu1w[(f0 + j) * Dc + d];
                const bf16 hi = (bf16)v;
                whi[d * 40 + f0 + j] = hi;
                wlo[d * 40 + f0 + j] = (bf16)(v - (float)hi);
            }
        }
        {   // W2s[d][e] from fp32 W2
            const int row = t >> 2, c0 = (t & 3) * 16;
            const float4 v0 = *(const float4*)&W2[row * 64 + c0];
            const float4 v1 = *(const float4*)&W2[row * 64 + c0 + 4];
            const float4 v2 = *(const float4*)&W2[row * 64 + c0 + 8];
            const float4 v3 = *(const float4*)&W2[row * 64 + c0 + 12];
            bf16x8 p0, p1;
            p0[0]=(bf16)v0.x; p0[1]=(bf16)v0.y; p0[2]=(bf16)v0.z; p0[3]=(bf16)v0.w;
            p0[4]=(bf16)v1.x; p0[5]=(bf16)v1.y; p0[6]=(bf16)v1.z; p0[7]=(bf16)v1.w;
            p1[0]=(bf16)v2.x; p1[1]=(bf16)v2.y; p1[2]=(bf16)v2.z; p1[3]=(bf16)v2.w;
            p1[4]=(bf16)v3.x; p1[5]=(bf16)v3.y; p1[6]=(bf16)v3.z; p1[7]=(bf16)v3.w;
            *(bf16x8*)&W2s[row * MS + c0] = p0;
            *(bf16x8*)&W2s[row * MS + c0 + 8] = p1;
        }
        __syncthreads();
        f32x4 acc[4];
#pragma unroll
        for (int ct = 0; ct < 4; ++ct)
#pragma unroll
            for (int r = 0; r < 4; ++r) acc[ct][r] = 0.f;
        {
            const bf16x8 aHi = *(const bf16x8*)&xhi[(wv * 16 + lm) * 40 + q * 8];
            const bf16x8 aLo = *(const bf16x8*)&xlo[(wv * 16 + lm) * 40 + q * 8];
#pragma unroll
            for (int ct = 0; ct < 4; ++ct) {
                const bf16x8 bHi = *(const bf16x8*)&whi[(ct * 16 + lm) * 40 + q * 8];
                const bf16x8 bLo = *(const bf16x8*)&wlo[(ct * 16 + lm) * 40 + q * 8];
                acc[ct] = __builtin_amdgcn_mfma_f32_16x16x32_bf16(aHi, bHi, acc[ct], 0, 0, 0);
                acc[ct] = __builtin_amdgcn_mfma_f32_16x16x32_bf16(aLo, bHi, acc[ct], 0, 0, 0);
                acc[ct] = __builtin_amdgcn_mfma_f32_16x16x32_bf16(aHi, bLo, acc[ct], 0, 0, 0);
            }
        }
#pragma unroll
        for (int ct = 0; ct < 4; ++ct) {
            const int col = ct * 16 + lm;
#pragma unroll
            for (int r = 0; r < 4; ++r) {
                const int row = wv * 16 + q * 4 + r;
                const float v = fmaxf(acc[ct][r], 0.f);
                mu_1[((size_t)b * Nc + n0 + row) * Dc + col] = v;
                muS[row * MS + col] = (bf16)v;
            }
        }
        __syncthreads();
        f32x4 xacc[4];
#pragma unroll
        for (int ct = 0; ct < 4; ++ct)
#pragma unroll
            for (int r = 0; r < 4; ++r) xacc[ct][r] = 0.f;
#pragma unroll
        for (int s = 0; s < 2; ++s) {
            bf16x8 a = *(const bf16x8*)&muS[(wv * 16 + lm) * MS + s * 32 + q * 8];
#pragma unroll
            for (int ct = 0; ct < 4; ++ct) {
                bf16x8 bv = *(const bf16x8*)&W2s[(ct * 16 + lm) * MS + s * 32 + q * 8];
                xacc[ct] = __builtin_amdgcn_mfma_f32_16x16x32_bf16(a, bv, xacc[ct], 0, 0, 0);
            }
        }
        // store Xfrag0: g=ct, k0=nb*2+(wv>>1), q_c=(wv&1)*2+(q>>1), j0=(q&1)*4
        const int k0 = nb * 2 + (wv >> 1);
        const int q_c = (wv & 1) * 2 + (q >> 1);
        const int j0 = (q & 1) * 4;
#pragma unroll
        for (int ct = 0; ct < 4; ++ct) {
            bf16x4 p;
#pragma unroll
            for (int r = 0; r < 4; ++r) p[r] = (bf16)xacc[ct][r];
            *(bf16x4*)&Xfrag0[(size_t)b * 65536
                              + (size_t)((ct * 32 + k0) * 64 + lm + 16 * q_c) * 8 + j0] = p;
        }
    }
}

// ---------------------------------------------------------------------------
// k_round: barrier-free coalesced K-loop on fragment-major A/X.
// grid (Bc, 16) = 512 blocks, 256 thr = 4 waves (rh = n-half, ch = d-half).
// Epilogue: mu = relu(mu_1+P+C3); non-final: Xfrag_out = mu@W2^T; final: head.
// ---------------------------------------------------------------------------
template <bool FINAL>
__global__ __launch_bounds__(256, 2)
void k_round(const bf16* __restrict__ Afrag, const bf16* __restrict__ Xfr_in,
             const float* __restrict__ mu_1, const float* __restrict__ C3,
             const bf16* __restrict__ W2bf, bf16* __restrict__ Xfr_out,
             const float* __restrict__ Wreg, const float* __restrict__ c2base,
             const float* __restrict__ Wq, const float* __restrict__ bq,
             float* __restrict__ musum, float* __restrict__ out) {
    const int b = blockIdx.x, nb = blockIdx.y, t = threadIdx.x;
    const int n0 = nb * 64;
    const int l = t & 63, wv = t >> 6, lm = l & 15, q = l >> 4;
    const int rh = wv & 1, ch = wv >> 1;
    extern __shared__ char smem[];
    bf16* muHi = (bf16*)smem;                     // [64][72]
    bf16* muLo = (bf16*)(smem + 9216);            // FINAL only
    bf16* WHi  = (bf16*)(smem + (FINAL ? 18432 : 9216));
    bf16* WLo  = (bf16*)(smem + 27648);           // FINAL only
    float* rpart = (float*)(smem + 36864);        // FINAL [2][64]

    if (!FINAL) {
#pragma unroll
        for (int i = 0; i < 2; ++i) {
            int g = i * 256 + t, row = g >> 3, c = g & 7;
            *(bf16x8*)&WHi[row * MS + c * 8] = *(const bf16x8*)&W2bf[row * 64 + c * 8];
        }
    } else {
#pragma unroll
        for (int i = 0; i < 4; ++i) {
            int g = i * 1024 + t * 4, h = g >> 6, d = g & 63;
            const float4 w4 = *(const float4*)&Wreg[h * 128 + d];
            bf16x4 ohi, olo;
            ohi[0] = (bf16)w4.x; olo[0] = (bf16)(w4.x - (float)ohi[0]);
            ohi[1] = (bf16)w4.y; olo[1] = (bf16)(w4.y - (float)ohi[1]);
            ohi[2] = (bf16)w4.z; olo[2] = (bf16)(w4.z - (float)ohi[2]);
            ohi[3] = (bf16)w4.w; olo[3] = (bf16)(w4.w - (float)ohi[3]);
            *(bf16x4*)&WHi[h * MS + d] = ohi;
            *(bf16x4*)&WLo[h * MS + d] = olo;
        }
    }

    // ---- K-loop: coalesced fragment streaming, no barriers ----
    f32x4 acc[2][2];
#pragma unroll
    for (int rt = 0; rt < 2; ++rt)
#pragma unroll
        for (int ct = 0; ct < 2; ++ct)
#pragma unroll
            for (int r = 0; r < 4; ++r) acc[rt][ct][r] = 0.f;

    const int gA = nb * 4 + rh * 2;
    const bf16* pa0 = Afrag + (size_t)(gA + 0) * 32 * 512 + l * 8;
    const bf16* pa1 = Afrag + (size_t)(gA + 1) * 32 * 512 + l * 8;
    const bf16* px0 = Xfr_in + (size_t)b * 65536 + (size_t)(ch * 2 + 0) * 32 * 512 + l * 8;
    const bf16* px1 = Xfr_in + (size_t)b * 65536 + (size_t)(ch * 2 + 1) * 32 * 512 + l * 8;
#pragma unroll 4
    for (int k0 = 0; k0 < 32; ++k0) {
        const int o = k0 * 512;
        bf16x8 a0 = *(const bf16x8*)&pa0[o];
        bf16x8 a1 = *(const bf16x8*)&pa1[o];
        bf16x8 x0 = *(const bf16x8*)&px0[o];
        bf16x8 x1 = *(const bf16x8*)&px1[o];
        acc[0][0] = __builtin_amdgcn_mfma_f32_16x16x32_bf16(a0, x0, acc[0][0], 0, 0, 0);
        acc[0][1] = __builtin_amdgcn_mfma_f32_16x16x32_bf16(a0, x1, acc[0][1], 0, 0, 0);
        acc[1][0] = __builtin_amdgcn_mfma_f32_16x16x32_bf16(a1, x0, acc[1][0], 0, 0, 0);
        acc[1][1] = __builtin_amdgcn_mfma_f32_16x16x32_bf16(a1, x1, acc[1][1], 0, 0, 0);
    }

    // ---- epilogue: mu = relu(mu_1 + P + C3) ----
    float vals[2][2][4];
#pragma unroll
    for (int rt = 0; rt < 2; ++rt)
#pragma unroll
        for (int ct = 0; ct < 2; ++ct) {
            const int col = ch * 32 + ct * 16 + lm;
#pragma unroll
            for (int r = 0; r < 4; ++r) {
                const int n = n0 + rh * 32 + rt * 16 + q * 4 + r;
                float v = mu_1[((size_t)b * Nc + n) * Dc + col] + acc[rt][ct][r]
                        + C3[n * 64 + col];
                vals[rt][ct][r] = fmaxf(v, 0.f);
            }
        }

#pragma unroll
    for (int rt = 0; rt < 2; ++rt)
#pragma unroll
        for (int ct = 0; ct < 2; ++ct) {
            const int col = ch * 32 + ct * 16 + lm;
#pragma unroll
            for (int r = 0; r < 4; ++r) {
                const int row = rh * 32 + rt * 16 + q * 4 + r;
                const float v = vals[rt][ct][r];
                const bf16 hi = (bf16)v;
                muHi[row * MS + col] = hi;
                if (FINAL) muLo[row * MS + col] = (bf16)(v - (float)hi);
            }
        }
    if (FINAL) {
#pragma unroll
        for (int ct = 0; ct < 2; ++ct) {
            float s = 0.f;
#pragma unroll
            for (int rt = 0; rt < 2; ++rt)
#pragma unroll
                for (int r = 0; r < 4; ++r) s += vals[rt][ct][r];
            s += __shfl_xor(s, 16);
            s += __shfl_xor(s, 32);
            if (q == 0) atomicAdd(&musum[b * 64 + ch * 32 + ct * 16 + lm], s);
        }
    }
    __syncthreads();

    f32x4 xacc[2][2];
#pragma unroll
    for (int rt = 0; rt < 2; ++rt)
#pragma unroll
        for (int ct = 0; ct < 2; ++ct)
#pragma unroll
            for (int r = 0; r < 4; ++r) xacc[rt][ct][r] = 0.f;

    if (!FINAL) {
#pragma unroll
        for (int s = 0; s < 2; ++s) {
            bf16x8 aM[2], bW[2];
#pragma unroll
            for (int rt = 0; rt < 2; ++rt)
                aM[rt] = *(const bf16x8*)&muHi[(rh * 32 + rt * 16 + lm) * MS + s * 32 + q * 8];
#pragma unroll
            for (int ct = 0; ct < 2; ++ct)
                bW[ct] = *(const bf16x8*)&WHi[(ch * 32 + ct * 16 + lm) * MS + s * 32 + q * 8];
#pragma unroll
            for (int rt = 0; rt < 2; ++rt)
#pragma unroll
                for (int ct = 0; ct < 2; ++ct)
                    xacc[rt][ct] = __builtin_amdgcn_mfma_f32_16x16x32_bf16(aM[rt], bW[ct],
                                                                           xacc[rt][ct], 0, 0, 0);
        }
        // store Xfrag_out: g=ch*2+ct, k0=nb*2+rh, q_c=rt*2+(q>>1), j0=(q&1)*4
        const int k0 = nb * 2 + rh;
        const int q_c0 = (q >> 1), j0 = (q & 1) * 4;
#pragma unroll
        for (int rt = 0; rt < 2; ++rt)
#pragma unroll
            for (int ct = 0; ct < 2; ++ct) {
                bf16x4 p;
#pragma unroll
                for (int r = 0; r < 4; ++r) p[r] = (bf16)xacc[rt][ct][r];
                *(bf16x4*)&Xfr_out[(size_t)b * 65536
                    + (size_t)(((ch * 2 + ct) * 32 + k0) * 64 + lm + 16 * (rt * 2 + q_c0)) * 8
                    + j0] = p;
            }
    } else {
        // head: P2 = muHi@WHi + muLo@WHi + muHi@WLo (split precision)
#pragma unroll
        for (int s = 0; s < 2; ++s) {
            bf16x8 aH[2], aL[2], bH[2], bL[2];
#pragma unroll
            for (int rt = 0; rt < 2; ++rt) {
                const int ao = (rh * 32 + rt * 16 + lm) * MS + s * 32 + q * 8;
                aH[rt] = *(const bf16x8*)&muHi[ao];
                aL[rt] = *(const bf16x8*)&muLo[ao];
            }
#pragma unroll
            for (int ct = 0; ct < 2; ++ct) {
                const int bo = (ch * 32 + ct * 16 + lm) * MS + s * 32 + q * 8;
                bH[ct] = *(const bf16x8*)&WHi[bo];
                bL[ct] = *(const bf16x8*)&WLo[bo];
            }
#pragma unroll
            for (int rt = 0; rt < 2; ++rt)
#pragma unroll
                for (int ct = 0; ct < 2; ++ct) {
                    xacc[rt][ct] = __builtin_amdgcn_mfma_f32_16x16x32_bf16(aH[rt], bH[ct],
                                                                           xacc[rt][ct], 0, 0, 0);
                    xacc[rt][ct] = __builtin_amdgcn_mfma_f32_16x16x32_bf16(aL[rt], bH[ct],
                                                                           xacc[rt][ct], 0, 0, 0);
                    xacc[rt][ct] = __builtin_amdgcn_mfma_f32_16x16x32_bf16(aH[rt], bL[ct],
                                                                           xacc[rt][ct], 0, 0, 0);
                }
        }
        const float bq0 = bq[0];
        float rowsum[2][4] = {{0.f, 0.f, 0.f, 0.f}, {0.f, 0.f, 0.f, 0.f}};
#pragma unroll
        for (int ct = 0; ct < 2; ++ct) {
            const int h = ch * 32 + ct * 16 + lm;
            const float c2 = c2base[b * 64 + h];
            const float wqh = Wq[h];
#pragma unroll
            for (int rt = 0; rt < 2; ++rt)
#pragma unroll
                for (int r = 0; r < 4; ++r)
                    rowsum[rt][r] += fmaxf(xacc[rt][ct][r] + c2, 0.f) * wqh;
        }
#pragma unroll
        for (int rt = 0; rt < 2; ++rt)
#pragma unroll
            for (int r = 0; r < 4; ++r) {
                float v = rowsum[rt][r];
                v += __shfl_xor(v, 1);
                v += __shfl_xor(v, 2);
                v += __shfl_xor(v, 4);
                v += __shfl_xor(v, 8);
                if (lm == 0) rpart[ch * 64 + rh * 32 + rt * 16 + q * 4 + r] = v;
            }
        __syncthreads();
        if (t < 64)
            out[(size_t)b * (Nc + 1) + n0 + t] = rpart[t] + rpart[64 + t] + bq0;
    }
}

// ---------------------------------------------------------------------------
// k_tail: mean row. grid B, block 64 (fp32)
// ---------------------------------------------------------------------------
__global__ void k_tail(const float* __restrict__ musum, const float* __restrict__ Wq1,
                       const float* __restrict__ bq1, const float* __restrict__ Wreg,
                       const float* __restrict__ c2base, const float* __restrict__ Wq,
                       const float* __restrict__ bq, float* __restrict__ out) {
    const int b = blockIdx.x, l = threadIdx.x;
    __shared__ float mean_s[64];
    __shared__ float mp[64];
    mean_s[l] = musum[b * 64 + l] * (1.f / Nc);
    __syncthreads();
    float a = bq1[l];
#pragma unroll
    for (int e = 0; e < 64; ++e) a = fmaf(mean_s[e], Wq1[l * 64 + e], a);
    mp[l] = fmaxf(a, 0.f);
    __syncthreads();
    float h = c2base[b * 64 + l];
#pragma unroll
    for (int d = 0; d < 64; ++d) h = fmaf(mp[d], Wreg[l * 128 + d], h);
    float v = fmaxf(h, 0.f) * Wq[l];
#pragma unroll
    for (int off = 32; off; off >>= 1) v += __shfl_down(v, off);
    if (l == 0) out[(size_t)b * (Nc + 1) + Nc] = v + bq[0];
}

// ---------------------------------------------------------------------------
extern "C" void kernel_launch(void* const* d_in, const int* in_sizes, int n_in,
                              void* d_out, int out_size, void* d_ws, size_t ws_size,
                              hipStream_t stream) {
    const float* xv     = (const float*)d_in[0];
    const float* option = (const float*)d_in[1];
    const float* adj    = (const float*)d_in[2];
    const float* mu1w   = (const float*)d_in[3];
    const float* W2     = (const float*)d_in[4];
    const float* b2     = (const float*)d_in[5];
    const float* W3     = (const float*)d_in[6];
    const float* b3     = (const float*)d_in[7];
    const float* W4     = (const float*)d_in[8];
    const float* b4     = (const float*)d_in[9];
    const float* Wq1    = (const float*)d_in[10];
    const float* bq1    = (const float*)d_in[11];
    const float* Wq2    = (const float*)d_in[12];
    const float* bq2    = (const float*)d_in[13];
    const float* Wreg   = (const float*)d_in[14];
    const float* breg   = (const float*)d_in[15];
    const float* Wq     = (const float*)d_in[16];
    const float* bq     = (const float*)d_in[17];
    float* out = (float*)d_out;

    float* ws = (float*)d_ws;
    const size_t MU = (size_t)Bc * Nc * Dc;          // 2,097,152
    float* mu_1     = ws;
    float* C3       = ws + MU;                       // 65536
    float* c2base   = C3 + 65536;                    // 2048
    float* musum    = c2base + 2048;                 // 2048
    bf16*  Afrag    = (bf16*)(musum + 2048);         // 1M bf16
    bf16*  W2bf     = Afrag + (size_t)Nc * Nc;       // 4096 bf16
    bf16*  Xf0      = W2bf + 4096;                   // B*64K bf16
    bf16*  Xf1      = Xf0 + MU;

    k_init<<<1537, 256, 0, stream>>>(adj, W4, b4, W3, b3, b2, W2, option, Wq2, bq2,
                                     Wreg, breg, xv, mu1w,
                                     Afrag, C3, W2bf, c2base, musum, mu_1, Xf0);
    k_round<false><<<dim3(Bc, 16), 256, LDS_RND_NONF, stream>>>(
        Afrag, Xf0, mu_1, C3, W2bf, Xf1,
        nullptr, nullptr, nullptr, nullptr, nullptr, nullptr);
    k_round<false><<<dim3(Bc, 16), 256, LDS_RND_NONF, stream>>>(
        Afrag, Xf1, mu_1, C3, W2bf, Xf0,
        nullptr, nullptr, nullptr, nullptr, nullptr, nullptr);
    k_round<true><<<dim3(Bc, 16), 256, LDS_RND_FIN, stream>>>(
        Afrag, Xf0, mu_1, C3, nullptr, nullptr,
        Wreg, c2base, Wq, bq, musum, out);
    k_tail<<<Bc, 64, 0, stream>>>(musum, Wq1, bq1, Wreg, c2base, Wq, bq, out);
}